// Round 1
// baseline (222.351 us; speedup 1.0000x reference)
//
#include <hip/hip_runtime.h>
#include <hip/hip_bf16.h>

#define IMG 256

// Zero the output image (harness poisons d_out with 0xAA before every launch).
__global__ void zero_kernel(float4* __restrict__ out, int n4) {
    int i = blockIdx.x * blockDim.x + threadIdx.x;
    if (i < n4) out[i] = make_float4(0.f, 0.f, 0.f, 0.f);
}

// Perspective projection -> NDC xy, replicating the numpy float32 op order
// exactly (each op individually rounded; no fma contraction).
__global__ void project_kernel(const float* __restrict__ verts,
                               const float* __restrict__ cams,
                               float2* __restrict__ ndc, int B, int V) {
    int i = blockIdx.x * blockDim.x + threadIdx.x;
    if (i >= B * V) return;
    int b = i / V;
    // f = norm_f * cam[b,0] + norm_f0  (norm_f=1, norm_f0=0)
    float f  = __fadd_rn(__fmul_rn(1.0f, cams[b * 3 + 0]), 0.0f);
    float cx = cams[b * 3 + 1];
    float cy = cams[b * 3 + 2];
    float image_size = __fmul_rn(cams[1], 2.0f);  // cam[0,1] * 2.0
    float x = verts[3 * i + 0];
    float y = verts[3 * i + 1];
    float z = __fadd_rn(verts[3 * i + 2], 0.0f);  // + norm_z (0)
    float px = __fadd_rn(__fdiv_rn(__fmul_rn(f, x), z), cx);
    float py = __fadd_rn(__fdiv_rn(__fmul_rn(f, y), z), cy);
    float nx = __fsub_rn(__fmul_rn(__fdiv_rn(px, image_size), 2.0f), 1.0f);
    float ny = __fsub_rn(__fmul_rn(__fdiv_rn(py, image_size), 2.0f), 1.0f);
    ndc[i] = make_float2(nx, ny);
}

// One wave (64 lanes) per face: bbox sweep, exact-fp32 edge tests, plain
// stores of 1.0f (write-write races all store the identical value -> benign).
__global__ void raster_kernel(const float2* __restrict__ ndc,
                              const int* __restrict__ faces,
                              float* __restrict__ out, int B, int V, int F) {
    int gid  = blockIdx.x * blockDim.x + threadIdx.x;
    int wave = gid >> 6;
    int lane = gid & 63;
    if (wave >= B * F) return;
    int b  = wave / F;
    int fi = wave - b * F;
    const int* fp = faces + (size_t)(b * F + fi) * 3;
    float2 v0 = ndc[b * V + fp[0]];
    float2 v1 = ndc[b * V + fp[1]];
    float2 v2 = ndc[b * V + fp[2]];

    // area = (v1x-v0x)*(v2y-v0y) - (v1y-v0y)*(v2x-v0x), exact np fp32 order
    float area = __fsub_rn(
        __fmul_rn(__fsub_rn(v1.x, v0.x), __fsub_rn(v2.y, v0.y)),
        __fmul_rn(__fsub_rn(v1.y, v0.y), __fsub_rn(v2.x, v0.x)));
    if (!(fabsf(area) > 1e-12f)) return;  // matches: valid = |area| > 1e-12

    // Conservative bbox in pixel-index space. center(i) = (2i+1)/256 - 1
    // => i = 128*ndc + 127.5. Widen by 1 px each side (cull only; fp slop ok).
    float xmn = fminf(v0.x, fminf(v1.x, v2.x));
    float xmx = fmaxf(v0.x, fmaxf(v1.x, v2.x));
    float ymn = fminf(v0.y, fminf(v1.y, v2.y));
    float ymx = fmaxf(v0.y, fmaxf(v1.y, v2.y));
    int ix0 = max(0,       (int)floorf(xmn * 128.0f + 127.5f) - 1);
    int ix1 = min(IMG - 1, (int)ceilf (xmx * 128.0f + 127.5f) + 1);
    int iy0 = max(0,       (int)floorf(ymn * 128.0f + 127.5f) - 1);
    int iy1 = min(IMG - 1, (int)ceilf (ymx * 128.0f + 127.5f) + 1);
    if (ix1 < ix0 || iy1 < iy0) return;

    // Loop-invariant edge deltas (each sub individually rounded, matching np)
    float e0x = __fsub_rn(v2.x, v1.x), e0y = __fsub_rn(v2.y, v1.y);
    float e1x = __fsub_rn(v0.x, v2.x), e1y = __fsub_rn(v0.y, v2.y);
    float e2x = __fsub_rn(v1.x, v0.x), e2y = __fsub_rn(v1.y, v0.y);

    float* outb = out + (size_t)b * IMG * IMG;
    for (int y = iy0; y <= iy1; ++y) {
        float py = (2.0f * (float)y + 1.0f) * 0.00390625f - 1.0f;  // exact
        // row-constant second terms of each edge function
        float t0 = __fmul_rn(__fsub_rn(py, v1.y), e0x);
        float t1 = __fmul_rn(__fsub_rn(py, v2.y), e1x);
        float t2 = __fmul_rn(__fsub_rn(py, v0.y), e2x);
        float* row = outb + (size_t)y * IMG;
        for (int x = ix0 + lane; x <= ix1; x += 64) {
            float px = (2.0f * (float)x + 1.0f) * 0.00390625f - 1.0f;  // exact
            float w0 = __fsub_rn(__fmul_rn(__fsub_rn(px, v1.x), e0y), t0);
            float w1 = __fsub_rn(__fmul_rn(__fsub_rn(px, v2.x), e1y), t1);
            float w2 = __fsub_rn(__fmul_rn(__fsub_rn(px, v0.x), e2y), t2);
            bool pos = (w0 >= 0.f) & (w1 >= 0.f) & (w2 >= 0.f);
            bool neg = (w0 <= 0.f) & (w1 <= 0.f) & (w2 <= 0.f);
            if (pos | neg) row[x] = 1.0f;
        }
    }
}

extern "C" void kernel_launch(void* const* d_in, const int* in_sizes, int n_in,
                              void* d_out, int out_size, void* d_ws, size_t ws_size,
                              hipStream_t stream) {
    const float* verts = (const float*)d_in[0];
    const int*   faces = (const int*)d_in[1];
    const float* cams  = (const float*)d_in[2];
    float* out = (float*)d_out;

    int B = in_sizes[2] / 3;            // cams [B,3]
    int V = in_sizes[0] / (3 * B);      // vertices [B,V,3]
    int F = in_sizes[1] / (3 * B);      // faces [B,F,3]

    float2* ndc = (float2*)d_ws;        // B*V float2 = ~62 KB scratch

    int n4 = out_size / 4;
    hipLaunchKernelGGL(zero_kernel, dim3((n4 + 255) / 256), dim3(256), 0, stream,
                       (float4*)d_out, n4);
    hipLaunchKernelGGL(project_kernel, dim3((B * V + 255) / 256), dim3(256), 0, stream,
                       verts, cams, ndc, B, V);
    int nthreads = B * F * 64;          // one wave per face
    hipLaunchKernelGGL(raster_kernel, dim3((nthreads + 255) / 256), dim3(256), 0, stream,
                       ndc, faces, out, B, V, F);
}

// Round 2
// 114.553 us; speedup vs baseline: 1.9410x; 1.9410x over previous
//
#include <hip/hip_runtime.h>
#include <hip/hip_bf16.h>

#define IMG 256
#define SPLIT 4  // row-block waves per face (load-balance smoothing)

// Fused: zero the output image AND project vertices to NDC (saves a launch).
// Projection replicates numpy float32 op order exactly (no fma contraction).
__global__ void init_kernel(const float* __restrict__ verts,
                            const float* __restrict__ cams,
                            float4* __restrict__ out4, int n4,
                            float2* __restrict__ ndc, int BV, int V) {
    int i = blockIdx.x * blockDim.x + threadIdx.x;
    if (i < n4) out4[i] = make_float4(0.f, 0.f, 0.f, 0.f);
    if (i < BV) {
        int b = i / V;
        float f  = __fadd_rn(__fmul_rn(1.0f, cams[b * 3 + 0]), 0.0f);
        float cx = cams[b * 3 + 1];
        float cy = cams[b * 3 + 2];
        float image_size = __fmul_rn(cams[1], 2.0f);  // cam[0,1] * 2.0
        float x = verts[3 * i + 0];
        float y = verts[3 * i + 1];
        float z = __fadd_rn(verts[3 * i + 2], 0.0f);
        float px = __fadd_rn(__fdiv_rn(__fmul_rn(f, x), z), cx);
        float py = __fadd_rn(__fdiv_rn(__fmul_rn(f, y), z), cy);
        float nx = __fsub_rn(__fmul_rn(__fdiv_rn(px, image_size), 2.0f), 1.0f);
        float ny = __fsub_rn(__fmul_rn(__fdiv_rn(py, image_size), 2.0f), 1.0f);
        ndc[i] = make_float2(nx, ny);
    }
}

// SPLIT waves per face. Each wave picks the lane tile shape (64x1 / 32x2 /
// 16x4 / 8x8) minimizing iteration count for the face's bbox, then sweeps
// every SPLIT-th row-block. Edge tests bit-identical to numpy fp32.
__global__ __launch_bounds__(256) void raster_kernel(
        const float2* __restrict__ ndc, const int* __restrict__ faces,
        float* __restrict__ out, int B, int V, int F) {
    int gid  = blockIdx.x * blockDim.x + threadIdx.x;
    int wave = gid >> 6;
    int lane = gid & 63;
    int widx = wave >> 2;        // face index (SPLIT=4)
    int sub  = wave & (SPLIT - 1);
    if (widx >= B * F) return;
    int b  = widx / F;
    const int* fp = faces + (size_t)widx * 3;
    const float2* nb = ndc + (size_t)b * V;
    float2 v0 = nb[fp[0]];
    float2 v1 = nb[fp[1]];
    float2 v2 = nb[fp[2]];

    // area = (v1x-v0x)*(v2y-v0y) - (v1y-v0y)*(v2x-v0x), exact np fp32 order
    float area = __fsub_rn(
        __fmul_rn(__fsub_rn(v1.x, v0.x), __fsub_rn(v2.y, v0.y)),
        __fmul_rn(__fsub_rn(v1.y, v0.y), __fsub_rn(v2.x, v0.x)));
    if (!(fabsf(area) > 1e-12f)) return;

    // Conservative bbox in pixel space: center(i) = (2i+1)/256-1 => i = 128*v+127.5
    float xmn = fminf(v0.x, fminf(v1.x, v2.x));
    float xmx = fmaxf(v0.x, fmaxf(v1.x, v2.x));
    float ymn = fminf(v0.y, fminf(v1.y, v2.y));
    float ymx = fmaxf(v0.y, fmaxf(v1.y, v2.y));
    int ix0 = max(0,       (int)floorf(xmn * 128.0f + 127.5f) - 1);
    int ix1 = min(IMG - 1, (int)ceilf (xmx * 128.0f + 127.5f) + 1);
    int iy0 = max(0,       (int)floorf(ymn * 128.0f + 127.5f) - 1);
    int iy1 = min(IMG - 1, (int)ceilf (ymx * 128.0f + 127.5f) + 1);
    if (ix1 < ix0 || iy1 < iy0) return;
    int W = ix1 - ix0 + 1, H = iy1 - iy0 + 1;

    // Pick lane tile shape (TWxTH, TW*TH=64) minimizing wave-iterations.
    int tws = 6, bestIt = ((W + 63) >> 6) * H;
    int it;
    it = ((W + 31) >> 5) * ((H + 1) >> 1); if (it < bestIt) { bestIt = it; tws = 5; }
    it = ((W + 15) >> 4) * ((H + 3) >> 2); if (it < bestIt) { bestIt = it; tws = 4; }
    it = ((W + 7)  >> 3) * ((H + 7) >> 3); if (it < bestIt) { bestIt = it; tws = 3; }
    int TW = 1 << tws, TH = 64 >> tws;
    int dx = lane & (TW - 1), dy = lane >> tws;

    // Loop-invariant edge deltas (each sub individually rounded, matching np)
    float e0x = __fsub_rn(v2.x, v1.x), e0y = __fsub_rn(v2.y, v1.y);
    float e1x = __fsub_rn(v0.x, v2.x), e1y = __fsub_rn(v0.y, v2.y);
    float e2x = __fsub_rn(v1.x, v0.x), e2y = __fsub_rn(v1.y, v0.y);

    float* outb = out + (size_t)b * IMG * IMG;
    float pxStep = (float)TW * 0.0078125f;  // TW*2/256, exact in fp32

    for (int ty = iy0 + sub * TH; ty <= iy1; ty += SPLIT * TH) {
        int y = ty + dy;
        bool yok = (y <= iy1);
        // pixel centers (2k+1)/256-1 are exactly representable in fp32
        float py = (float)(2 * y + 1) * 0.00390625f - 1.0f;
        float t0 = __fmul_rn(__fsub_rn(py, v1.y), e0x);
        float t1 = __fmul_rn(__fsub_rn(py, v2.y), e1x);
        float t2 = __fmul_rn(__fsub_rn(py, v0.y), e2x);
        float* p = outb + y * IMG + ix0 + dx;
        int x = ix0 + dx;
        float px = (float)(2 * x + 1) * 0.00390625f - 1.0f;
        for (int tx = ix0; tx <= ix1; tx += TW) {
            float w0 = __fsub_rn(__fmul_rn(__fsub_rn(px, v1.x), e0y), t0);
            float w1 = __fsub_rn(__fmul_rn(__fsub_rn(px, v2.x), e1y), t1);
            float w2 = __fsub_rn(__fmul_rn(__fsub_rn(px, v0.x), e2y), t2);
            float mn = fminf(w0, fminf(w1, w2));   // v_min3
            float mx = fmaxf(w0, fmaxf(w1, w2));   // v_max3
            bool inside = (mn >= 0.f) | (mx <= 0.f);  // all>=0 or all<=0
            if (inside & yok & (x <= ix1)) *p = 1.0f;
            px += pxStep;  // exact increment, bit-identical to direct eval
            x  += TW;
            p  += TW;
        }
    }
}

extern "C" void kernel_launch(void* const* d_in, const int* in_sizes, int n_in,
                              void* d_out, int out_size, void* d_ws, size_t ws_size,
                              hipStream_t stream) {
    const float* verts = (const float*)d_in[0];
    const int*   faces = (const int*)d_in[1];
    const float* cams  = (const float*)d_in[2];
    float* out = (float*)d_out;

    int B = in_sizes[2] / 3;
    int V = in_sizes[0] / (3 * B);
    int F = in_sizes[1] / (3 * B);

    float2* ndc = (float2*)d_ws;  // B*V float2

    int n4 = out_size / 4;
    int initThreads = max(n4, B * V);
    hipLaunchKernelGGL(init_kernel, dim3((initThreads + 255) / 256), dim3(256), 0,
                       stream, verts, cams, (float4*)d_out, n4, ndc, B * V, V);

    long long nthreads = (long long)B * F * SPLIT * 64;
    hipLaunchKernelGGL(raster_kernel, dim3((nthreads + 255) / 256), dim3(256), 0,
                       stream, ndc, faces, out, B, V, F);
}